// Round 9
// baseline (305.629 us; speedup 1.0000x reference)
//
#include <hip/hip_runtime.h>
#include <hip/hip_bf16.h>
#include <stdint.h>

#define B_ 4
#define H_ 16
#define S_ 2048
#define D_ 64
#define NKT (S_ / 64)
#define QM 128

typedef __attribute__((ext_vector_type(8))) short bf16x8;
typedef __attribute__((ext_vector_type(4))) float f32x4;
typedef unsigned long long u64;
typedef unsigned int u32;

// hardware packed f32->bf16 (RNE). No builtin on gfx950 (m240) -> inline asm.
__device__ inline u32 cvt_pk_bf16(float lo, float hi) {
  u32 r;
  asm("v_cvt_pk_bf16_f32 %0, %1, %2" : "=v"(r) : "v"(lo), "v"(hi));
  return r;
}

// XOR-swizzled byte offset in a row x 128-byte tile image
__device__ inline int SW(int row, int byteoff) {
  return row * 128 + (byteoff ^ ((row & 7) << 4));
}

__device__ inline void gll16(const void* g, void* l) {
  __builtin_amdgcn_global_load_lds(
      (const __attribute__((address_space(1))) u32*)g,
      (__attribute__((address_space(3))) u32*)(uintptr_t)l, 16, 0, 0);
}

// ---------------- prepass kernel 1: K fp32 -> bf16 swizzled rows ----------------
// Latency-hiding restructure: 8 independent dwordx4 loads (128B fp32) in flight
// per thread BEFORE any convert; then 16 cvt_pk + 4x16B swizzled stores.
// Output image byte-identical to round-5 (XOR is 16B-granular).
__global__ __launch_bounds__(256)
void prep_k(const float* __restrict__ Kg, char* __restrict__ Ksw) {
  int idx = blockIdx.x * 256 + threadIdx.x;      // 64B-bf16 half-row index
  int row = idx >> 1, half = idx & 1;
  const float* src = Kg + (size_t)idx * 32;
  float4 v[8];
#pragma unroll
  for (int k = 0; k < 8; ++k) v[k] = *(const float4*)(src + k * 4);
  char* dstrow = Ksw + (size_t)row * 128;
  int xo = (row & 7) << 4;
#pragma unroll
  for (int j = 0; j < 4; ++j) {
    uint4 u;
    u.x = cvt_pk_bf16(v[2 * j].x, v[2 * j].y);
    u.y = cvt_pk_bf16(v[2 * j].z, v[2 * j].w);
    u.z = cvt_pk_bf16(v[2 * j + 1].x, v[2 * j + 1].y);
    u.w = cvt_pk_bf16(v[2 * j + 1].z, v[2 * j + 1].w);
    *(uint4*)(dstrow + (((4 * half + j) * 16) ^ xo)) = u;
  }
}

// ---------------- prepass kernel 2: V fp32 -> bf16 transposed 64-key tiles ----------------
// (round-5 verified body, unchanged)
__global__ __launch_bounds__(256)
void prep_v(const float* __restrict__ Vg, char* __restrict__ Vsw) {
  __shared__ short tile[4096];
  const int vb = blockIdx.x, tid = threadIdx.x;
  char* ct = (char*)tile;
  int c4 = tid & 15, g = tid >> 4;
  const float* src = Vg + (size_t)vb * (64 * D_) + (size_t)(g * 4) * D_ + c4 * 4;
  float4 vv[4];
#pragma unroll
  for (int i = 0; i < 4; ++i) vv[i] = *(const float4*)(src + (size_t)i * D_);
  const float* vf = (const float*)vv;
#pragma unroll
  for (int dd = 0; dd < 4; ++dd) {
    uint2 u;
    u.x = cvt_pk_bf16(vf[0 * 4 + dd], vf[1 * 4 + dd]);
    u.y = cvt_pk_bf16(vf[2 * 4 + dd], vf[3 * 4 + dd]);
    *(uint2*)(ct + SW(c4 * 4 + dd, g * 8)) = u;
  }
  __syncthreads();
  char* dst = Vsw + (size_t)vb * 8192;
#pragma unroll
  for (int j = 0; j < 2; ++j)
    *(float4*)(dst + tid * 16 + j * 4096) = *(const float4*)(ct + tid * 16 + j * 4096);
}

// ---------------- prepass kernel 3: mask int32 -> packed u64 bits ----------------
// Latency-hiding restructure: 16 independent dword loads (4 chunks) in flight
// per wave-iter before the 16 ballots; 4 grid-stride iters. Word mapping
// unchanged: Mp[chunk*4+j] <-> elements (chunk*4+j)*64.
__global__ __launch_bounds__(256)
void prep_m(const int* __restrict__ Mg, u64* __restrict__ Mp) {
  const int tid = threadIdx.x;
  const int lane = tid & 63;
  const int gwave = blockIdx.x * 4 + (tid >> 6);   // 4096 waves total
  for (int c0 = gwave * 4; c0 < (B_ * S_ * S_ / 256); c0 += 4096 * 4) {
    int vals[4][4];
#pragma unroll
    for (int cj = 0; cj < 4; ++cj) {
      const int* src = Mg + (size_t)(c0 + cj) * 256;
#pragma unroll
      for (int j = 0; j < 4; ++j) vals[cj][j] = src[j * 64 + lane];
    }
#pragma unroll
    for (int cj = 0; cj < 4; ++cj) {
      u64 bits[4];
#pragma unroll
      for (int j = 0; j < 4; ++j) bits[j] = __ballot(vals[cj][j] != 0);
      if (lane == 0) {
        ulonglong4 o;
        o.x = bits[0]; o.y = bits[1]; o.z = bits[2]; o.w = bits[3];
        *(ulonglong4*)(Mp + (size_t)(c0 + cj) * 4) = o;
      }
    }
  }
}

// ---------------- main kernel (EXACT round-5 verified text) ----------------
// Swapped-operand QK^T (S^T); in-register P->A transform via asm cvt_pk +
// permlane32/16 swaps (verified round 2). l via MFMA ones-column (verified
// round 3). kt loop unrolled x2 (constexpr buffer parity). XCD swizzle keeps
// all 16 q-blocks of one bh on the same XCD (FETCH 148->41MB, verified round 3).
__global__ __launch_bounds__(256, 4)
void attn_kernel(const float* __restrict__ Qg,
                 const char* __restrict__ Ksw,
                 const char* __restrict__ Vsw,
                 const u64* __restrict__ Mp,
                 float* __restrict__ Og) {
  __shared__ short sK[2][4096];
  __shared__ short sV[2][4096];

  const int tid  = threadIdx.x;
  const int w    = tid >> 6;
  const int lane = tid & 63;
  const int quad = lane >> 4;
  const int c    = lane & 15;

  // XCD swizzle: flat%8 decides XCD. bh = (flat&7) | ((flat>>7)<<3), qi = (flat>>3)&15.
  const int flat = blockIdx.x + (int)gridDim.x * blockIdx.y;   // gridDim.x == 16
  const int bh   = (flat & 7) | ((flat >> 7) << 3);
  const int q0   = ((flat >> 3) & 15) * QM;
  const int b    = bh >> 4;            // H_ == 16

  const size_t base = (size_t)bh * (S_ * D_);
  const char* Kt = Ksw + (size_t)bh * (S_ * 128);
  const char* Vt = Vsw + (size_t)bh * (S_ * 128);
  char* cK0 = (char*)sK;               // 16 KB contiguous, doubles as Q stage

  // ---- stage Q (pre-scaled into log2 domain) into the sK area ----
  const float SC = 0.125f * 1.44269504088896f;   // 1/sqrt(64) * log2(e)
#pragma unroll
  for (int j = 0; j < 8; ++j) {
    int idx = tid + j * 256;
    int row = idx >> 4, c4 = idx & 15;
    float4 v = *(const float4*)(Qg + base + (size_t)(q0 + row) * D_ + c4 * 4);
    uint2 u;
    u.x = cvt_pk_bf16(v.x * SC, v.y * SC);
    u.y = cvt_pk_bf16(v.z * SC, v.w * SC);
    *(uint2*)(cK0 + SW(row, c4 * 8)) = u;
  }
  __syncthreads();
  bf16x8 qa[2][2];
#pragma unroll
  for (int gi = 0; gi < 2; ++gi) {
    qa[gi][0] = *(bf16x8*)(cK0 + SW(32 * w + 16 * gi + c, quad * 16));
    qa[gi][1] = *(bf16x8*)(cK0 + SW(32 * w + 16 * gi + c, 64 + quad * 16));
  }
  __syncthreads();   // all Q reads done; sK area may now be overwritten

  // issue tile-0 async staging
#pragma unroll
  for (int j = 0; j < 2; ++j) {
    gll16(Kt + tid * 16 + j * 4096, (char*)sK[0] + tid * 16 + j * 4096);
    gll16(Vt + tid * 16 + j * 4096, (char*)sV[0] + tid * 16 + j * 4096);
  }

  // loop-invariant swizzled ds offsets (same formula serves K and V reads)
  int koff[4][2];
#pragma unroll
  for (int n = 0; n < 4; ++n) {
    koff[n][0] = SW(16 * n + c, quad * 16);
    koff[n][1] = SW(16 * n + c, 64 + quad * 16);
  }

  // all-ones bf16 B operand for the l column (layout-free: every element 1.0)
  bf16x8 ones;
#pragma unroll
  for (int i = 0; i < 8; ++i) ones[i] = (short)0x3F80;

  f32x4 acco[2][4];
  f32x4 acc_l[2];
#pragma unroll
  for (int gi = 0; gi < 2; ++gi) {
    acc_l[gi] = f32x4{0, 0, 0, 0};
#pragma unroll
    for (int i = 0; i < 4; ++i) acco[gi][i] = f32x4{0, 0, 0, 0};
  }

  // one u64 mask word per lane per gi per tile: row = q0+32w+16gi+c
  const u64* mrowp = Mp + ((size_t)b * S_ + q0 + 32 * w + c) * NKT;

  const char* kbase = (const char*)sK;
  const char* vbase = (const char*)sV;

  for (int kt2 = 0; kt2 < NKT; kt2 += 2) {
#pragma unroll
    for (int p = 0; p < 2; ++p) {
      const int kt = kt2 + p;

      __syncthreads();   // gll(kt) drained; prev-iter V reads done

      u64 mw[2];
      mw[0] = mrowp[kt];
      mw[1] = mrowp[16 * NKT + kt];

      // ---- scores: S^T = K Q^T (lane holds qrow=c, keys 16n + 4*quad + r) ----
      f32x4 accs[2][4];
      __builtin_amdgcn_s_setprio(1);
#pragma unroll
      for (int n = 0; n < 4; ++n) {
        bf16x8 kb0 = *(bf16x8*)(kbase + koff[n][0] + p * 8192);
        bf16x8 kb1 = *(bf16x8*)(kbase + koff[n][1] + p * 8192);
#pragma unroll
        for (int gi = 0; gi < 2; ++gi) {
          f32x4 z = {0, 0, 0, 0};
          z = __builtin_amdgcn_mfma_f32_16x16x32_bf16(kb0, qa[gi][0], z, 0, 0, 0);
          z = __builtin_amdgcn_mfma_f32_16x16x32_bf16(kb1, qa[gi][1], z, 0, 0, 0);
          accs[gi][n] = z;
        }
      }
      __builtin_amdgcn_s_setprio(0);

      // async prefetch tile kt+1 into parity p^1; in flight through exp+PV,
      // drained at the next barrier.
      if (kt + 1 < NKT) {
        char* kn = (char*)sK + (p ^ 1) * 8192;
        char* vn = (char*)sV + (p ^ 1) * 8192;
        const char* kg = Kt + (size_t)(kt + 1) * 8192;
        const char* vg = Vt + (size_t)(kt + 1) * 8192;
#pragma unroll
        for (int j = 0; j < 2; ++j) {
          gll16(kg + tid * 16 + j * 4096, kn + tid * 16 + j * 4096);
          gll16(vg + tid * 16 + j * 4096, vn + tid * 16 + j * 4096);
        }
      }

      // ---- softmax numerator + in-register C->A transform ----
      bf16x8 pa[2][2];
#pragma unroll
      for (int gi = 0; gi < 2; ++gi) {
        u32 mlo = (u32)(mw[gi] >> (4 * quad));        // bits: n=0 -> r, n=1 -> 16+r
        u32 mhi = (u32)(mw[gi] >> (4 * quad + 32));   // bits: n=2 -> r, n=3 -> 16+r
        float e[4][4];
#pragma unroll
        for (int n = 0; n < 4; ++n) {
          u32 mword = (n < 2) ? mlo : mhi;
          int sh = 16 * (n & 1);
#pragma unroll
          for (int r = 0; r < 4; ++r) {
            float sm = ((mword >> (sh + r)) & 1u) ? accs[gi][n][r] : -1000.0f;
            e[n][r] = exp2f(sm);                       // bare v_exp_f32; exp2(-1000)=+0
          }
        }

        // pack pairs: pk[n][h] = bf16(keys 16n+4quad+2h, +1)
        u32 pk[4][2];
#pragma unroll
        for (int n = 0; n < 4; ++n) {
          pk[n][0] = cvt_pk_bf16(e[n][0], e[n][1]);
          pk[n][1] = cvt_pk_bf16(e[n][2], e[n][3]);
        }

        // lane-routing network (vdst = even-n, vsrc = odd-n; verified round 2)
#pragma unroll
        for (int t = 0; t < 2; ++t) {
          union { bf16x8 v; u32 uw[4]; } pu;
#pragma unroll
          for (int h = 0; h < 2; ++h) {
            u32 a  = pk[2 * t][h];       // vdst = X (n = 2t)
            u32 bq = pk[2 * t + 1][h];   // vsrc = Y (n = 2t+1)
            asm("v_permlane32_swap_b32 %0, %1" : "+v"(a), "+v"(bq));
            asm("v_permlane16_swap_b32 %0, %1" : "+v"(a), "+v"(bq));
            pu.uw[h]     = a;            // W_A: keys 32t + 8*quad + 2h, +1
            pu.uw[2 + h] = bq;           // W_B: keys 32t + 8*quad + 4 + 2h, +1
          }
          pa[gi][t] = pu.v;
        }
      }

      // ---- O += P V ; l += P · 1 (ones-column MFMA) ----
      __builtin_amdgcn_s_setprio(1);
#pragma unroll
      for (int dn = 0; dn < 4; ++dn) {
        bf16x8 vb0 = *(bf16x8*)(vbase + koff[dn][0] + p * 8192);
        bf16x8 vb1 = *(bf16x8*)(vbase + koff[dn][1] + p * 8192);
#pragma unroll
        for (int gi = 0; gi < 2; ++gi) {
          acco[gi][dn] = __builtin_amdgcn_mfma_f32_16x16x32_bf16(pa[gi][0], vb0, acco[gi][dn], 0, 0, 0);
          acco[gi][dn] = __builtin_amdgcn_mfma_f32_16x16x32_bf16(pa[gi][1], vb1, acco[gi][dn], 0, 0, 0);
        }
      }
#pragma unroll
      for (int gi = 0; gi < 2; ++gi) {
        acc_l[gi] = __builtin_amdgcn_mfma_f32_16x16x32_bf16(pa[gi][0], ones, acc_l[gi], 0, 0, 0);
        acc_l[gi] = __builtin_amdgcn_mfma_f32_16x16x32_bf16(pa[gi][1], ones, acc_l[gi], 0, 0, 0);
      }
      __builtin_amdgcn_s_setprio(0);
    }
  }

  // ---- epilogue: acc_l[gi][r] is l for exactly the row this lane stores ----
#pragma unroll
  for (int gi = 0; gi < 2; ++gi) {
#pragma unroll
    for (int r = 0; r < 4; ++r) {
      float inv = 1.0f / acc_l[gi][r];
      size_t orow = base + (size_t)(q0 + 32 * w + 16 * gi + quad * 4 + r) * D_;
#pragma unroll
      for (int dn = 0; dn < 4; ++dn)
        Og[orow + 16 * dn + c] = acco[gi][dn][r] * inv;
    }
  }
}

extern "C" void kernel_launch(void* const* d_in, const int* in_sizes, int n_in,
                              void* d_out, int out_size, void* d_ws, size_t ws_size,
                              hipStream_t stream) {
  const float* Kg = (const float*)d_in[0];  // key
  const float* Qg = (const float*)d_in[1];  // query
  const float* Vg = (const float*)d_in[2];  // value
  const int*   Mg = (const int*)d_in[3];    // mask
  float* Og = (float*)d_out;

  char* ws  = (char*)d_ws;
  u64*  Mp  = (u64*)ws;                                  // 2 MiB
  char* Ksw = ws + (size_t)(2u << 20);                   // 16 MiB
  char* Vsw = ws + (size_t)(2u << 20) + (16u << 20);     // 16 MiB

  prep_k<<<1024, 256, 0, stream>>>(Kg, Ksw);   // 262144 threads x 32 floats
  prep_v<<<2048, 256, 0, stream>>>(Vg, Vsw);
  prep_m<<<1024, 256, 0, stream>>>(Mg, Mp);
  attn_kernel<<<dim3(S_ / QM, B_ * H_), 256, 0, stream>>>(Qg, Ksw, Vsw, Mp, Og);
}